// Round 1
// baseline (74.446 us; speedup 1.0000x reference)
//
#include <hip/hip_runtime.h>
#include <hip/hip_bf16.h>

// Problem constants (from reference setup)
#define NSX   8
#define NSUB  64
#define GRIDP 64
#define HID   32
#define OUT   32
#define TRES  64
#define T_TOT 4096   // TRES*TRES
#define S_TOT 512    // B*NSUB

typedef __attribute__((ext_vector_type(8))) short short8;   // 8 bf16 = 4 VGPRs (MFMA A/B frag)
typedef __attribute__((ext_vector_type(4))) float f32x4;    // MFMA C/D frag

__device__ __forceinline__ float gelu_exact(float x) {
    return 0.5f * x * (1.0f + erff(x * 0.70710678118654752440f));
}

__device__ __forceinline__ unsigned int f2bf_u(float x) {
    __hip_bfloat16 h = __float2bfloat16(x);
    unsigned short us = *reinterpret_cast<unsigned short*>(&h);
    return (unsigned int)us;
}

// ---------------------------------------------------------------------------
// Kernel 1: target-grid hidden activations g[t,c] = gelu(tgt_coords @ tw1 + tb1)
// stored as bf16, row-major [4096][32]
// ---------------------------------------------------------------------------
__global__ __launch_bounds__(256) void k_tgt_hidden(
    const float* __restrict__ tw1, const float* __restrict__ tb1,
    unsigned int* __restrict__ Gbf /* [4096][16] uint = [4096][32] bf16 */) {
    int t = blockIdx.x * 256 + threadIdx.x;
    if (t >= T_TOT) return;
    int i = t >> 6, j = t & 63;
    const double step = 0.25 / 63.0;
    float x = (float)(-0.125 + (double)j * step);
    float y = (float)(-0.125 + (double)i * step);
    unsigned int pk[16];
#pragma unroll
    for (int c2 = 0; c2 < 16; ++c2) {
        float z0 = fmaf(x, tw1[2 * c2],     fmaf(y, tw1[HID + 2 * c2],     tb1[2 * c2]));
        float z1 = fmaf(x, tw1[2 * c2 + 1], fmaf(y, tw1[HID + 2 * c2 + 1], tb1[2 * c2 + 1]));
        pk[c2] = f2bf_u(gelu_exact(z0)) | (f2bf_u(gelu_exact(z1)) << 16);
    }
    uint4* dst = (uint4*)(Gbf + (size_t)t * 16);
#pragma unroll
    for (int k = 0; k < 4; ++k)
        dst[k] = make_uint4(pk[4 * k], pk[4 * k + 1], pk[4 * k + 2], pk[4 * k + 3]);
}

// ---------------------------------------------------------------------------
// Kernel 2: per-segment pipeline. One block per segment s (512 blocks, 256 thr).
//   H[r][c]  = gelu(coords_r @ sw1 + sb1)                       (64x32)
//   M[c][h]  = sum_r H[r][c] * V[r][h]                          (32x32)
//   A[o][h]  = (sum_c M[c][h]*sw2[c,o*32+h] + sb2[o*32+h]*Vsum[h]) / 64
//   P[s,o,c] = sum_h tw2[c,o*32+h]*A[o][h]   -> bf16
//   q[s,o]   = sum_h tb2[o*32+h]*A[o][h]     -> f32
// Segment s = b*64 + cy*8 + cx contains points p = b*4096 + (cy*8+ri)*64 + cx*8+rj.
// ---------------------------------------------------------------------------
__global__ __launch_bounds__(256) void k_segment(
    const float* __restrict__ v, const float* __restrict__ coords,
    const float* __restrict__ sw1, const float* __restrict__ sb1,
    const float* __restrict__ sw2, const float* __restrict__ sb2,
    const float* __restrict__ tw2, const float* __restrict__ tb2,
    unsigned short* __restrict__ Pbf, float* __restrict__ qout) {
    const int s = blockIdx.x;
    const int b = s >> 6, cy = (s >> 3) & 7, cx = s & 7;
    const int tid = threadIdx.x;

    __shared__ float Hs[64][HID];
    __shared__ float Vs[64][HID];
    __shared__ float Ms[HID][HID];
    __shared__ float As[OUT][HID];
    __shared__ float Vsum[HID];

    // ---- load V (each thread: 8 floats) ----
    {
        int r = tid >> 2, q = tid & 3;
        int p = b * 4096 + (cy * 8 + (r >> 3)) * 64 + cx * 8 + (r & 7);
        const f32x4* src = (const f32x4*)(v + (size_t)p * HID + q * 8);
        f32x4 a0 = src[0], a1 = src[1];
        *(f32x4*)&Vs[r][q * 8]     = a0;
        *(f32x4*)&Vs[r][q * 8 + 4] = a1;
    }
    // ---- compute H (threads 0..63, one point each) ----
    if (tid < 64) {
        int r = tid;
        int p = b * 4096 + (cy * 8 + (r >> 3)) * 64 + cx * 8 + (r & 7);
        float x = coords[2 * p], y = coords[2 * p + 1];
#pragma unroll
        for (int c = 0; c < HID; ++c) {
            float z = fmaf(x, sw1[c], fmaf(y, sw1[HID + c], sb1[c]));
            Hs[r][c] = gelu_exact(z);
        }
    }
    __syncthreads();

    // ---- M phase: thread (c = tid/8, hq = tid%8), 4 h's each ----
    {
        int c = tid >> 3, hq = tid & 7;
        f32x4 acc = {0.f, 0.f, 0.f, 0.f};
#pragma unroll 16
        for (int r = 0; r < 64; ++r) {
            float hv = Hs[r][c];
            f32x4 vv = *(const f32x4*)&Vs[r][hq * 4];
            acc[0] = fmaf(hv, vv[0], acc[0]);
            acc[1] = fmaf(hv, vv[1], acc[1]);
            acc[2] = fmaf(hv, vv[2], acc[2]);
            acc[3] = fmaf(hv, vv[3], acc[3]);
        }
        *(f32x4*)&Ms[c][hq * 4] = acc;
    }
    if (tid < 32) {
        float sum = 0.f;
#pragma unroll 16
        for (int r = 0; r < 64; ++r) sum += Vs[r][tid];
        Vsum[tid] = sum;
    }
    __syncthreads();

    // ---- A phase: thread (o = tid/8, hq = tid%8) ----
    {
        int o = tid >> 3, hq = tid & 7;
        f32x4 acc = {0.f, 0.f, 0.f, 0.f};
#pragma unroll 8
        for (int c = 0; c < HID; ++c) {
            f32x4 w = *(const f32x4*)(sw2 + (size_t)c * 1024 + o * 32 + hq * 4);
            f32x4 m = *(const f32x4*)&Ms[c][hq * 4];
            acc[0] = fmaf(m[0], w[0], acc[0]);
            acc[1] = fmaf(m[1], w[1], acc[1]);
            acc[2] = fmaf(m[2], w[2], acc[2]);
            acc[3] = fmaf(m[3], w[3], acc[3]);
        }
        f32x4 bb = *(const f32x4*)(sb2 + o * 32 + hq * 4);
        f32x4 vs = *(const f32x4*)&Vsum[hq * 4];
        acc[0] = fmaf(bb[0], vs[0], acc[0]);
        acc[1] = fmaf(bb[1], vs[1], acc[1]);
        acc[2] = fmaf(bb[2], vs[2], acc[2]);
        acc[3] = fmaf(bb[3], vs[3], acc[3]);
        const float inv = 1.0f / 64.0f;
        acc[0] *= inv; acc[1] *= inv; acc[2] *= inv; acc[3] *= inv;
        *(f32x4*)&As[o][hq * 4] = acc;
    }
    __syncthreads();

    // ---- P phase: thread (o = tid/8, cq = tid%8), 4 c's each; q by cq==0 ----
    {
        int o = tid >> 3, cq = tid & 7;
        f32x4 a[8];
#pragma unroll
        for (int hq = 0; hq < 8; ++hq) a[hq] = *(const f32x4*)&As[o][hq * 4];

        unsigned int pk[2];
#pragma unroll
        for (int k2 = 0; k2 < 2; ++k2) {
            unsigned int w01 = 0;
#pragma unroll
            for (int kk = 0; kk < 2; ++kk) {
                int c = cq * 4 + k2 * 2 + kk;
                float acc = 0.f;
#pragma unroll
                for (int hq = 0; hq < 8; ++hq) {
                    f32x4 w = *(const f32x4*)(tw2 + (size_t)c * 1024 + o * 32 + hq * 4);
                    acc = fmaf(w[0], a[hq][0], acc);
                    acc = fmaf(w[1], a[hq][1], acc);
                    acc = fmaf(w[2], a[hq][2], acc);
                    acc = fmaf(w[3], a[hq][3], acc);
                }
                w01 |= f2bf_u(acc) << (16 * kk);
            }
            pk[k2] = w01;
        }
        uint2 val; val.x = pk[0]; val.y = pk[1];
        *(uint2*)(Pbf + (size_t)s * 1024 + o * 32 + cq * 4) = val;

        if (cq == 0) {
            float acc = 0.f;
#pragma unroll
            for (int hq = 0; hq < 8; ++hq) {
                f32x4 tb = *(const f32x4*)(tb2 + o * 32 + hq * 4);
                acc = fmaf(tb[0], a[hq][0], acc);
                acc = fmaf(tb[1], a[hq][1], acc);
                acc = fmaf(tb[2], a[hq][2], acc);
                acc = fmaf(tb[3], a[hq][3], acc);
            }
            qout[s * 32 + o] = acc;
        }
    }
}

// ---------------------------------------------------------------------------
// Kernel 3: u[s,t,o] = sum_c g[t,c]*P[s,o,c] + q[s,o] via bf16 MFMA 16x16x32.
// Grid (4, 512): block = (t-chunk of 1024, s). 4 waves, each wave 16 t-tiles.
// A-frag = G rows (global, no LDS), B-frag = P rows, C init = q.
// ---------------------------------------------------------------------------
__global__ __launch_bounds__(256) void k_contract(
    const unsigned short* __restrict__ Gbf,
    const unsigned short* __restrict__ Pbf,
    const float* __restrict__ q,
    float* __restrict__ u) {
    const int s    = blockIdx.y;
    const int lane = threadIdx.x & 63;
    const int wave = threadIdx.x >> 6;
    const int lo = lane & 15;       // A: m(t)-row | B: n(o)-col | D: col
    const int lk = lane >> 4;       // k-chunk of 8

    // B fragments: B[k=c][n=o] = P[s][o][c], lane holds P[s][lo][lk*8 + j]
    const short8* pb = (const short8*)(Pbf + (size_t)s * 1024);
    short8 b0 = pb[lo * 4 + lk];              // o-tile 0: o = lo
    short8 b1 = pb[(lo + 16) * 4 + lk];       // o-tile 1: o = lo + 16

    float q0 = q[s * 32 + lo];
    float q1 = q[s * 32 + 16 + lo];
    f32x4 c0 = {q0, q0, q0, q0};
    f32x4 c1 = {q1, q1, q1, q1};

    const int tbase = blockIdx.x * 1024 + wave * 256;
    float* ubase = u + (size_t)s * T_TOT * 32;

#pragma unroll 4
    for (int tile = 0; tile < 16; ++tile) {
        int t0 = tbase + tile * 16;
        // A fragment: A[m=t][k=c]: lane holds G[t0+lo][lk*8 + j]
        short8 afrag = *(const short8*)(Gbf + (size_t)(t0 + lo) * 32 + lk * 8);
        f32x4 d0 = __builtin_amdgcn_mfma_f32_16x16x32_bf16(afrag, b0, c0, 0, 0, 0);
        f32x4 d1 = __builtin_amdgcn_mfma_f32_16x16x32_bf16(afrag, b1, c1, 0, 0, 0);
        float* up = ubase + (size_t)t0 * 32;
#pragma unroll
        for (int j = 0; j < 4; ++j) {
            int row = lk * 4 + j;              // D: row = (lane>>4)*4 + reg
            up[row * 32 + lo]      = d0[j];
            up[row * 32 + 16 + lo] = d1[j];
        }
    }
}

// ---------------------------------------------------------------------------
extern "C" void kernel_launch(void* const* d_in, const int* in_sizes, int n_in,
                              void* d_out, int out_size, void* d_ws, size_t ws_size,
                              hipStream_t stream) {
    (void)in_sizes; (void)n_in; (void)out_size; (void)ws_size;
    const float* v       = (const float*)d_in[0];
    const float* scoords = (const float*)d_in[1];
    // d_in[2] = src_batch (implied by structure), d_in[3] = tgt_res (=64)
    const float* sw1 = (const float*)d_in[4];
    const float* sb1 = (const float*)d_in[5];
    const float* sw2 = (const float*)d_in[6];
    const float* sb2 = (const float*)d_in[7];
    const float* tw1 = (const float*)d_in[8];
    const float* tb1 = (const float*)d_in[9];
    const float* tw2 = (const float*)d_in[10];
    const float* tb2 = (const float*)d_in[11];
    float* u = (float*)d_out;

    char* ws = (char*)d_ws;
    unsigned int*   Gbf  = (unsigned int*)ws;                       // 4096*32*2   = 262144 B
    unsigned short* Pbf  = (unsigned short*)(ws + 262144);          // 512*1024*2  = 1048576 B
    float*          qbuf = (float*)(ws + 262144 + 1048576);         // 512*32*4    = 65536 B

    hipLaunchKernelGGL(k_tgt_hidden, dim3(16), dim3(256), 0, stream, tw1, tb1, Gbf);
    hipLaunchKernelGGL(k_segment, dim3(S_TOT), dim3(256), 0, stream,
                       v, scoords, sw1, sb1, sw2, sb2, tw2, tb2,
                       (unsigned short*)Pbf, qbuf);
    hipLaunchKernelGGL(k_contract, dim3(4, S_TOT), dim3(256), 0, stream,
                       (const unsigned short*)Gbf, (const unsigned short*)Pbf, qbuf, u);
}

// Round 3
// 72.982 us; speedup vs baseline: 1.0201x; 1.0201x over previous
//
#include <hip/hip_runtime.h>
#include <hip/hip_bf16.h>

// Problem constants (from reference setup)
#define HID   32
#define OUT   32
#define T_TOT 4096   // TRES*TRES
#define S_TOT 512    // B*NSUB

typedef __attribute__((ext_vector_type(8))) short short8;   // 8 bf16 = 4 VGPRs (MFMA A/B frag)
typedef __attribute__((ext_vector_type(4))) float f32x4;    // MFMA C/D frag

__device__ __forceinline__ float gelu_exact(float x) {
    return 0.5f * x * (1.0f + erff(x * 0.70710678118654752440f));
}

__device__ __forceinline__ unsigned int f2bf_u(float x) {
    __hip_bfloat16 h = __float2bfloat16(x);
    unsigned short us = *reinterpret_cast<unsigned short*>(&h);
    return (unsigned int)us;
}

// ---------------------------------------------------------------------------
// Kernel 1: target-grid hidden activations g[t,c] = gelu(tgt_coords @ tw1 + tb1)
// stored as bf16, row-major [4096][32]  (identical to R1's k_tgt_hidden)
// ---------------------------------------------------------------------------
__global__ __launch_bounds__(256) void k_tgt_hidden(
    const float* __restrict__ tw1, const float* __restrict__ tb1,
    unsigned int* __restrict__ Gbf /* [4096][16] uint = [4096][32] bf16 */) {
    int t = blockIdx.x * 256 + threadIdx.x;
    if (t >= T_TOT) return;
    int i = t >> 6, j = t & 63;
    const double step = 0.25 / 63.0;
    float x = (float)(-0.125 + (double)j * step);
    float y = (float)(-0.125 + (double)i * step);
    unsigned int pk[16];
#pragma unroll
    for (int c2 = 0; c2 < 16; ++c2) {
        float z0 = fmaf(x, tw1[2 * c2],     fmaf(y, tw1[HID + 2 * c2],     tb1[2 * c2]));
        float z1 = fmaf(x, tw1[2 * c2 + 1], fmaf(y, tw1[HID + 2 * c2 + 1], tb1[2 * c2 + 1]));
        pk[c2] = f2bf_u(gelu_exact(z0)) | (f2bf_u(gelu_exact(z1)) << 16);
    }
    uint4* dst = (uint4*)(Gbf + (size_t)t * 16);
#pragma unroll
    for (int k = 0; k < 4; ++k)
        dst[k] = make_uint4(pk[4 * k], pk[4 * k + 1], pk[4 * k + 2], pk[4 * k + 3]);
}

// ---------------------------------------------------------------------------
// Kernel 2: per-segment pipeline (R1 structure, separate LDS arrays, global
// P/q transport). Only change vs R1: H computed by all 256 threads (8 gelu
// per thread) instead of 32 gelu on 64 threads — bit-identical values.
// ---------------------------------------------------------------------------
__global__ __launch_bounds__(256) void k_segment(
    const float* __restrict__ v, const float* __restrict__ coords,
    const float* __restrict__ sw1, const float* __restrict__ sb1,
    const float* __restrict__ sw2, const float* __restrict__ sb2,
    const float* __restrict__ tw2, const float* __restrict__ tb2,
    unsigned short* __restrict__ Pbf, float* __restrict__ qout) {
    const int s = blockIdx.x;
    const int b = s >> 6, cy = (s >> 3) & 7, cx = s & 7;
    const int tid = threadIdx.x;

    __shared__ float Hs[64][HID];
    __shared__ float Vs[64][HID];
    __shared__ float Ms[HID][HID];
    __shared__ float As[OUT][HID];
    __shared__ float Vsum[HID];

    // ---- load V + compute H (thread = point r = tid/4, channel-oct qq = tid%4) ----
    {
        int r = tid >> 2, qq = tid & 3;
        int p = b * 4096 + (cy * 8 + (r >> 3)) * 64 + cx * 8 + (r & 7);
        const f32x4* src = (const f32x4*)(v + (size_t)p * HID + qq * 8);
        f32x4 a0 = src[0], a1 = src[1];
        *(f32x4*)&Vs[r][qq * 8]     = a0;
        *(f32x4*)&Vs[r][qq * 8 + 4] = a1;

        float x = coords[2 * p], y = coords[2 * p + 1];
#pragma unroll
        for (int e = 0; e < 8; ++e) {
            int c = qq * 8 + e;
            float z = fmaf(x, sw1[c], fmaf(y, sw1[HID + c], sb1[c]));
            Hs[r][c] = gelu_exact(z);
        }
    }
    __syncthreads();

    // ---- M phase: M[c][h] = sum_r H[r][c]*V[r][h] ----
    {
        int c = tid >> 3, hq = tid & 7;
        f32x4 acc = {0.f, 0.f, 0.f, 0.f};
#pragma unroll 16
        for (int r = 0; r < 64; ++r) {
            float hv = Hs[r][c];
            f32x4 vv = *(const f32x4*)&Vs[r][hq * 4];
            acc[0] = fmaf(hv, vv[0], acc[0]);
            acc[1] = fmaf(hv, vv[1], acc[1]);
            acc[2] = fmaf(hv, vv[2], acc[2]);
            acc[3] = fmaf(hv, vv[3], acc[3]);
        }
        *(f32x4*)&Ms[c][hq * 4] = acc;
    }
    if (tid < 32) {
        float sum = 0.f;
#pragma unroll 16
        for (int r = 0; r < 64; ++r) sum += Vs[r][tid];
        Vsum[tid] = sum;
    }
    __syncthreads();

    // ---- A phase: A[o][h] = (sum_c M[c][h]*sw2[c,o*32+h] + sb2[o*32+h]*Vsum[h]) / 64 ----
    {
        int o = tid >> 3, hq = tid & 7;
        f32x4 acc = {0.f, 0.f, 0.f, 0.f};
#pragma unroll 8
        for (int c = 0; c < HID; ++c) {
            f32x4 w = *(const f32x4*)(sw2 + (size_t)c * 1024 + o * 32 + hq * 4);
            f32x4 m = *(const f32x4*)&Ms[c][hq * 4];
            acc[0] = fmaf(m[0], w[0], acc[0]);
            acc[1] = fmaf(m[1], w[1], acc[1]);
            acc[2] = fmaf(m[2], w[2], acc[2]);
            acc[3] = fmaf(m[3], w[3], acc[3]);
        }
        f32x4 bb = *(const f32x4*)(sb2 + o * 32 + hq * 4);
        f32x4 vs = *(const f32x4*)&Vsum[hq * 4];
        acc[0] = fmaf(bb[0], vs[0], acc[0]);
        acc[1] = fmaf(bb[1], vs[1], acc[1]);
        acc[2] = fmaf(bb[2], vs[2], acc[2]);
        acc[3] = fmaf(bb[3], vs[3], acc[3]);
        const float inv = 1.0f / 64.0f;
        acc[0] *= inv; acc[1] *= inv; acc[2] *= inv; acc[3] *= inv;
        *(f32x4*)&As[o][hq * 4] = acc;
    }
    __syncthreads();

    // ---- P phase: P[s][o][c] (bf16) and q[s][o] to global ----
    {
        int o = tid >> 3, cq = tid & 7;
        f32x4 a[8];
#pragma unroll
        for (int hq = 0; hq < 8; ++hq) a[hq] = *(const f32x4*)&As[o][hq * 4];

        unsigned int pk[2];
#pragma unroll
        for (int k2 = 0; k2 < 2; ++k2) {
            unsigned int w01 = 0;
#pragma unroll
            for (int kk = 0; kk < 2; ++kk) {
                int c = cq * 4 + k2 * 2 + kk;
                float acc = 0.f;
#pragma unroll
                for (int hq = 0; hq < 8; ++hq) {
                    f32x4 w = *(const f32x4*)(tw2 + (size_t)c * 1024 + o * 32 + hq * 4);
                    acc = fmaf(w[0], a[hq][0], acc);
                    acc = fmaf(w[1], a[hq][1], acc);
                    acc = fmaf(w[2], a[hq][2], acc);
                    acc = fmaf(w[3], a[hq][3], acc);
                }
                w01 |= f2bf_u(acc) << (16 * kk);
            }
            pk[k2] = w01;
        }
        uint2 val; val.x = pk[0]; val.y = pk[1];
        *(uint2*)(Pbf + (size_t)s * 1024 + o * 32 + cq * 4) = val;

        if (cq == 0) {
            float acc = 0.f;
#pragma unroll
            for (int hq = 0; hq < 8; ++hq) {
                f32x4 tb = *(const f32x4*)(tb2 + o * 32 + hq * 4);
                acc = fmaf(tb[0], a[hq][0], acc);
                acc = fmaf(tb[1], a[hq][1], acc);
                acc = fmaf(tb[2], a[hq][2], acc);
                acc = fmaf(tb[3], a[hq][3], acc);
            }
            qout[s * 32 + o] = acc;
        }
    }
}

// ---------------------------------------------------------------------------
// Kernel 3: u[s,t,o] = sum_c G[t,c]*P[s,o,c] + q[s,o] via MFMA 16x16x32 bf16.
// Orientation: A = P (m = o), B = G (n = t). D regs = 4 consecutive o's of one
// output row -> global_store_dwordx4. Grid (4, 512), 4 waves/block.
// ---------------------------------------------------------------------------
__global__ __launch_bounds__(256) void k_contract(
    const unsigned short* __restrict__ Gbf,
    const unsigned short* __restrict__ Pbf,
    const float* __restrict__ q,
    float* __restrict__ u) {
    const int s    = blockIdx.y;
    const int lane = threadIdx.x & 63;
    const int wave = threadIdx.x >> 6;
    const int lo = lane & 15;       // A: m(o)-row | B: n(t)-col | D: col(t)
    const int lk = lane >> 4;       // k-chunk of 8 channels

    // A fragments: A[m=o][k=c] -> lane holds P[s][lo][lk*8+j] (tile0), P[s][16+lo][...] (tile1)
    const unsigned short* pb = Pbf + (size_t)s * 1024;
    short8 p0 = *(const short8*)(pb + lo * 32 + lk * 8);
    short8 p1 = *(const short8*)(pb + (16 + lo) * 32 + lk * 8);

    // C init: reg j <-> row m = o = lk*4 + j  (D/C mapping: row=(lane>>4)*4+reg)
    f32x4 c0, c1;
#pragma unroll
    for (int j = 0; j < 4; ++j) {
        c0[j] = q[s * 32 + lk * 4 + j];
        c1[j] = q[s * 32 + 16 + lk * 4 + j];
    }

    const int tbase = blockIdx.x * 1024 + wave * 256;
    float* ubase = u + (size_t)s * (T_TOT * 32);

#pragma unroll 4
    for (int tile = 0; tile < 16; ++tile) {
        int t0 = tbase + tile * 16;
        // B fragment: B[k=c][n=t]: lane holds G[t0+lo][lk*8 + j]
        short8 gfrag = *(const short8*)(Gbf + (size_t)(t0 + lo) * 32 + lk * 8);
        f32x4 d0 = __builtin_amdgcn_mfma_f32_16x16x32_bf16(p0, gfrag, c0, 0, 0, 0);
        f32x4 d1 = __builtin_amdgcn_mfma_f32_16x16x32_bf16(p1, gfrag, c1, 0, 0, 0);
        // lane writes u[s][t0+lo][lk*4 .. +3] and u[s][t0+lo][16+lk*4 .. +3]
        float* up = ubase + (size_t)(t0 + lo) * 32;
        *(f32x4*)(up + lk * 4)      = d0;
        *(f32x4*)(up + 16 + lk * 4) = d1;
    }
}

// ---------------------------------------------------------------------------
extern "C" void kernel_launch(void* const* d_in, const int* in_sizes, int n_in,
                              void* d_out, int out_size, void* d_ws, size_t ws_size,
                              hipStream_t stream) {
    (void)in_sizes; (void)n_in; (void)out_size; (void)ws_size;
    const float* v       = (const float*)d_in[0];
    const float* scoords = (const float*)d_in[1];
    // d_in[2] = src_batch (implied by structure), d_in[3] = tgt_res (=64)
    const float* sw1 = (const float*)d_in[4];
    const float* sb1 = (const float*)d_in[5];
    const float* sw2 = (const float*)d_in[6];
    const float* sb2 = (const float*)d_in[7];
    const float* tw1 = (const float*)d_in[8];
    const float* tb1 = (const float*)d_in[9];
    const float* tw2 = (const float*)d_in[10];
    const float* tb2 = (const float*)d_in[11];
    float* u = (float*)d_out;

    char* ws = (char*)d_ws;
    unsigned int*   Gbf  = (unsigned int*)ws;                       // 4096*32*2   = 262144 B
    unsigned short* Pbf  = (unsigned short*)(ws + 262144);          // 512*1024*2  = 1048576 B
    float*          qbuf = (float*)(ws + 262144 + 1048576);         // 512*32*4    = 65536 B

    hipLaunchKernelGGL(k_tgt_hidden, dim3(16), dim3(256), 0, stream, tw1, tb1, Gbf);
    hipLaunchKernelGGL(k_segment, dim3(S_TOT), dim3(256), 0, stream,
                       v, scoords, sw1, sb1, sw2, sb2, tw2, tb2,
                       Pbf, qbuf);
    hipLaunchKernelGGL(k_contract, dim3(4, S_TOT), dim3(256), 0, stream,
                       (const unsigned short*)Gbf, (const unsigned short*)Pbf, qbuf, u);
}